// Round 6
// baseline (320.788 us; speedup 1.0000x reference)
//
#include <hip/hip_runtime.h>

// ---------------------------------------------------------------------------
// Problem constants
// ---------------------------------------------------------------------------
#define V_PREV 16384
#define V_NEXT 65536
#define F_IN   512
#define F_OUT  256
#define NNZ_UP 65536
#define N_EDGE 524288

using f32x4 = __attribute__((ext_vector_type(4))) float;
using bfrag = __attribute__((ext_vector_type(8))) short;   // 8 x bf16

__device__ __forceinline__ ushort f2bf(float f) {
    union { float f; unsigned u; } v; v.f = f;
    unsigned r = (v.u + 0x7FFFu + ((v.u >> 16) & 1u)) >> 16;
    return (ushort)r;
}
__device__ __forceinline__ float bf2f(ushort h) {
    union { unsigned u; float f; } v; v.u = ((unsigned)h) << 16; return v.f;
}

// ---------------------------------------------------------------------------
// Weight prep (transpose + bf16, concat Uj|Ui; bias1 Ui-half folds b_res)
// ---------------------------------------------------------------------------
__global__ void prep_weights_kernel(const float* __restrict__ Wres,
                                    const float* __restrict__ Ui0W, const float* __restrict__ Uj0W,
                                    const float* __restrict__ Ui1W, const float* __restrict__ Uj1W,
                                    const float* __restrict__ Ui1b, const float* __restrict__ Uj1b,
                                    const float* __restrict__ bres,
                                    ushort* __restrict__ WresT, ushort* __restrict__ W0t,
                                    ushort* __restrict__ W1t, float* __restrict__ bias1)
{
    int i = blockIdx.x * blockDim.x + threadIdx.x;   // 0 .. 512*512-1
    if (i < 256 * 512) {
        int n = i / 512, k = i % 512;
        WresT[i] = f2bf(Wres[k * 256 + n]);
    }
    if (i < 512 * 512) {
        int n = i / 512, k = i % 512;
        W0t[i] = f2bf(n < 256 ? Uj0W[k * 256 + n] : Ui0W[k * 256 + (n - 256)]);
    }
    if (i < 512 * 256) {
        int n = i / 256, k = i % 256;
        W1t[i] = f2bf(n < 256 ? Uj1W[k * 256 + n] : Ui1W[k * 256 + (n - 256)]);
    }
    if (i < 512) bias1[i] = (i < 256) ? Uj1b[i] : (Ui1b[i - 256] + bres[i - 256]);
}

// ---------------------------------------------------------------------------
// Up-map invert + CSR build
// ---------------------------------------------------------------------------
__global__ void invert_up_kernel(const int* __restrict__ up_row, const int* __restrict__ up_col,
                                 const float* __restrict__ up_val,
                                 int* __restrict__ colof, float* __restrict__ valof)
{
    int k = blockIdx.x * blockDim.x + threadIdx.x;
    int r = up_row[k];
    colof[r] = up_col[k];
    valof[r] = up_val[k];
}

__global__ void hist_kernel(const int* __restrict__ dst, const float* __restrict__ adjv,
                            int* __restrict__ cnt, float* __restrict__ sumA)
{
    int e = blockIdx.x * blockDim.x + threadIdx.x;
    int d = dst[e];
    atomicAdd(&cnt[d], 1);
    atomicAdd(&sumA[d], adjv[e]);
}

__global__ void scan_block_kernel(const int* __restrict__ cnt, int* __restrict__ offs,
                                  int* __restrict__ bsum)
{
    __shared__ int buf[2][256];
    int t = threadIdx.x;
    int i = blockIdx.x * 256 + t;
    int v = cnt[i];
    int p = 0;
    buf[0][t] = v;
    __syncthreads();
    for (int d = 1; d < 256; d <<= 1) {
        int nv = buf[p][t] + ((t >= d) ? buf[p][t - d] : 0);
        buf[p ^ 1][t] = nv;
        p ^= 1;
        __syncthreads();
    }
    int incl = buf[p][t];
    offs[i] = incl - v;
    if (t == 255) bsum[blockIdx.x] = incl;
}

__global__ void scan_top_kernel(const int* __restrict__ bsum, int* __restrict__ boff)
{
    __shared__ int buf[2][256];
    int t = threadIdx.x;
    int v = bsum[t];
    int p = 0;
    buf[0][t] = v;
    __syncthreads();
    for (int d = 1; d < 256; d <<= 1) {
        int nv = buf[p][t] + ((t >= d) ? buf[p][t - d] : 0);
        buf[p ^ 1][t] = nv;
        p ^= 1;
        __syncthreads();
    }
    boff[t] = buf[p][t] - v;
}

__global__ void add_offs_kernel(int* __restrict__ offs, const int* __restrict__ boff,
                                int* __restrict__ cursor)
{
    int i = blockIdx.x * 256 + threadIdx.x;
    int o = offs[i] + boff[blockIdx.x];
    offs[i] = o;
    cursor[i] = o;
}

// fill dst-sorted edge arrays; layer-0 variant pre-composes the up map:
//   srcs0 = colof[src], vals0 = adjv * valof[src]; layer-1 keeps (src, adjv)
__global__ void fill_kernel(const int* __restrict__ src, const int* __restrict__ dst,
                            const float* __restrict__ adjv,
                            const int* __restrict__ colof, const float* __restrict__ valof,
                            int* __restrict__ cursor,
                            int* __restrict__ srcsA, float* __restrict__ valsA,
                            int* __restrict__ srcs0, float* __restrict__ vals0)
{
    int e = blockIdx.x * blockDim.x + threadIdx.x;
    int d = dst[e];
    int s = src[e];
    float a = adjv[e];
    int p = atomicAdd(&cursor[d], 1);
    srcsA[p] = s;
    valsA[p] = a;
    srcs0[p] = colof[s];
    vals0[p] = a * valof[s];
}

// ---------------------------------------------------------------------------
// BatchNorm stats
// ---------------------------------------------------------------------------
__global__ void bn0_part_kernel(const float* __restrict__ x,
                                float* __restrict__ psum, float* __restrict__ psq)
{
    int blk = blockIdx.x, t = threadIdx.x;
    float s0 = 0, s1 = 0, q0 = 0, q1 = 0;
    for (int r = 0; r < 128; r++) {
        size_t base = ((size_t)blk * 128 + r) * 512;
        float a = x[base + t], b = x[base + t + 256];
        s0 += a; q0 += a * a; s1 += b; q1 += b * b;
    }
    psum[blk * 512 + t] = s0; psum[blk * 512 + t + 256] = s1;
    psq [blk * 512 + t] = q0; psq [blk * 512 + t + 256] = q1;
}

__global__ void bn1_part_bf16_kernel(const ushort* __restrict__ xx,
                                     float* __restrict__ psum, float* __restrict__ psq)
{
    int blk = blockIdx.x, t = threadIdx.x;
    float s = 0, q = 0;
    for (int r = 0; r < 128; r++) {
        float a = bf2f(xx[((size_t)blk * 128 + r) * 256 + t]);
        s += a; q += a * a;
    }
    psum[blk * 256 + t] = s; psq[blk * 256 + t] = q;
}

// Parallel finish: one wave per channel; produces sc = g*rstd, sh = b - mean*sc
__global__ void bn_finish_kernel(const float* __restrict__ psum, const float* __restrict__ psq,
                                 int nblocks, int C, float invN,
                                 const float* __restrict__ g, const float* __restrict__ b,
                                 float* __restrict__ sc, float* __restrict__ sh)
{
    int gw = (blockIdx.x * blockDim.x + threadIdx.x) >> 6;   // channel
    int lane = threadIdx.x & 63;
    if (gw >= C) return;
    float s = 0, q = 0;
    for (int i = lane; i < nblocks; i += 64) {
        s += psum[(size_t)i * C + gw];
        q += psq [(size_t)i * C + gw];
    }
#pragma unroll
    for (int d = 32; d > 0; d >>= 1) {
        s += __shfl_xor(s, d);
        q += __shfl_xor(q, d);
    }
    if (lane == 0) {
        float m = s * invN;
        float v = q * invN - m * m;
        float r = rsqrtf(v + 1e-5f);
        float scale = r * g[gw];
        sc[gw] = scale;
        sh[gw] = b[gw] - m * scale;
    }
}

// bn1 apply, in place on X1: X1 = bf16(relu(sc*X1 + sh))
__global__ void bn1_apply_kernel(ushort* __restrict__ X1,
                                 const float* __restrict__ sc, const float* __restrict__ sh)
{
    size_t i4 = ((size_t)blockIdx.x * blockDim.x + threadIdx.x) * 4;
    if (i4 >= (size_t)V_NEXT * F_OUT) return;
    ushort4 v = *(const ushort4*)&X1[i4];
    const ushort* vp = (const ushort*)&v;
    int c = (int)(i4 & 255);
    ushort ns[4];
#pragma unroll
    for (int j = 0; j < 4; j++) {
        float t = bf2f(vp[j]) * sc[c + j] + sh[c + j];
        ns[j] = f2bf(fmaxf(t, 0.0f));
    }
    *(ushort4*)&X1[i4] = make_ushort4(ns[0], ns[1], ns[2], ns[3]);
}

// ---------------------------------------------------------------------------
// GEMM0 fused: reads x f32 [16384,512] directly.
//   bx 0,1: XW  = bf16(x) @ WresT^T              (raw A)   cols 0..255
//   bx 2,3: XNJ = relu(bn0(x)) @ Uj0             cols 0..255 of W0t
//   bx 4,5: XNI = relu(bn0(x)) @ Ui0             cols 256..511 of W0t
// 128x128 tile, BK=32. LDS linear [row][32] + XOR unit^(row&3):
// conflict-free writes AND reads (2-way max, free per m136).
// ---------------------------------------------------------------------------
__global__ __launch_bounds__(256)
void gemm0_fused_kernel(const float* __restrict__ x,
                        const ushort* __restrict__ WresT, const ushort* __restrict__ W0t,
                        const float* __restrict__ sc0, const float* __restrict__ sh0,
                        ushort* __restrict__ XW, ushort* __restrict__ XNJ,
                        ushort* __restrict__ XNI)
{
    __shared__ ushort As[128 * 32];
    __shared__ ushort Bs[128 * 32];
    __shared__ float s_sc[512], s_sh[512];

    const int tid = threadIdx.x;
    const int bx = blockIdx.x;
    const bool bnmode = bx >= 2;
    const ushort* Bt = bnmode ? W0t : WresT;
    const int btrow = bnmode ? (bx - 2) * 128 : bx * 128;   // row base in Bt
    ushort* Cout = (bx < 2) ? XW : (bx < 4 ? XNJ : XNI);
    const int colbase = (bx & 1) * 128;                      // col base in 256-wide out
    const int tM = blockIdx.y * 128;

    for (int i = tid; i < 512; i += 256) { s_sc[i] = sc0[i]; s_sh[i] = sh0[i]; }
    __syncthreads();

    const int lane = tid & 63;
    const int wave = tid >> 6;
    const int wm = wave >> 1, wn = wave & 1;
    const int lr = lane & 15, lg = lane >> 4;

    const int ra = tid >> 1;            // A row 0..127
    const int ua = (tid & 1) * 2;       // first of two 16B units
    const int rb = tid >> 2;            // B fill row (x2 iters)
    const int ub = tid & 3;

    f32x4 acc[4][4] = {};

    for (int k0 = 0; k0 < 512; k0 += 32) {
        // --- A stage: 16 f32 -> bf16 (optional bn+relu), 2 units ---
        const float* xp = &x[(size_t)(tM + ra) * 512 + k0 + ua * 8];
        float4 f0 = *(const float4*)(xp);
        float4 f1 = *(const float4*)(xp + 4);
        float4 f2 = *(const float4*)(xp + 8);
        float4 f3 = *(const float4*)(xp + 12);
        float vv[16] = { f0.x,f0.y,f0.z,f0.w, f1.x,f1.y,f1.z,f1.w,
                         f2.x,f2.y,f2.z,f2.w, f3.x,f3.y,f3.z,f3.w };
        ushort hh[16];
        if (bnmode) {
#pragma unroll
            for (int j = 0; j < 16; j++) {
                int c = k0 + ua * 8 + j;
                hh[j] = f2bf(fmaxf(vv[j] * s_sc[c] + s_sh[c], 0.0f));
            }
        } else {
#pragma unroll
            for (int j = 0; j < 16; j++) hh[j] = f2bf(vv[j]);
        }
        *(uint4*)&As[ra * 32 + ((ua    ) ^ (ra & 3)) * 8] = *(uint4*)&hh[0];
        *(uint4*)&As[ra * 32 + ((ua + 1) ^ (ra & 3)) * 8] = *(uint4*)&hh[8];

        // --- B stage: 2 units per thread ---
#pragma unroll
        for (int i = 0; i < 2; i++) {
            int row = rb + i * 64;
            *(uint4*)&Bs[row * 32 + (ub ^ (row & 3)) * 8] =
                *(const uint4*)&Bt[(size_t)(btrow + row) * 512 + k0 + ub * 8];
        }
        __syncthreads();

        bfrag af[4], bfv[4];
#pragma unroll
        for (int mm = 0; mm < 4; mm++) {
            int row = wm * 64 + mm * 16 + lr;
            af[mm] = *(const bfrag*)&As[row * 32 + (lg ^ (row & 3)) * 8];
        }
#pragma unroll
        for (int nn = 0; nn < 4; nn++) {
            int row = wn * 64 + nn * 16 + lr;
            bfv[nn] = *(const bfrag*)&Bs[row * 32 + (lg ^ (row & 3)) * 8];
        }
#pragma unroll
        for (int mm = 0; mm < 4; mm++)
#pragma unroll
            for (int nn = 0; nn < 4; nn++)
                acc[mm][nn] = __builtin_amdgcn_mfma_f32_16x16x32_bf16(af[mm], bfv[nn], acc[mm][nn], 0, 0, 0);
        __syncthreads();
    }

#pragma unroll
    for (int mm = 0; mm < 4; mm++)
#pragma unroll
        for (int nn = 0; nn < 4; nn++)
#pragma unroll
            for (int r = 0; r < 4; r++) {
                int row = tM + wm * 64 + mm * 16 + lg * 4 + r;
                int col = colbase + wn * 64 + nn * 16 + lr;
                Cout[(size_t)row * 256 + col] = f2bf(acc[mm][nn][r]);
            }
}

// ---------------------------------------------------------------------------
// GEMM1 clean: A = H1 (bn already applied) [65536,256] bf16; Bt = W1t [512][256].
// grid (2, 512): block = 128 rows x 256 cols; BK=32; acc[4][8]; 24KB LDS.
//   bx 0 -> YJ  (bf16) = A @ Uj1 + Uj1_b
//   bx 1 -> UIb (bf16) = A @ Ui1 + (Ui1_b + b_res) + up_val*XW[up_col]
// ---------------------------------------------------------------------------
__global__ __launch_bounds__(256, 2)
void gemm1_clean_kernel(const ushort* __restrict__ H1, const ushort* __restrict__ W1t,
                        const float* __restrict__ bias1,
                        const int* __restrict__ colof, const float* __restrict__ valof,
                        const ushort* __restrict__ XW,
                        ushort* __restrict__ YJ, ushort* __restrict__ UIb)
{
    __shared__ ushort As[128 * 32];
    __shared__ ushort Bs[256 * 32];

    const int tid = threadIdx.x;
    const int bx = blockIdx.x;           // 0: Uj half, 1: Ui half
    const int tM = blockIdx.y * 128;
    const int tN = bx * 256;

    const int lane = tid & 63;
    const int wave = tid >> 6;
    const int wm = wave >> 1, wn = wave & 1;   // wave tile 64 rows x 128 cols
    const int lr = lane & 15, lg = lane >> 4;

    f32x4 acc[4][8] = {};

    for (int k0 = 0; k0 < 256; k0 += 32) {
        // --- A stage: 512 units, 2 per thread ---
#pragma unroll
        for (int i = 0; i < 2; i++) {
            int idx = tid + i * 256;
            int row = idx >> 2, u = idx & 3;
            *(uint4*)&As[row * 32 + (u ^ (row & 3)) * 8] =
                *(const uint4*)&H1[(size_t)(tM + row) * 256 + k0 + u * 8];
        }
        // --- B stage: 1024 units, 4 per thread ---
#pragma unroll
        for (int i = 0; i < 4; i++) {
            int idx = tid + i * 256;
            int row = idx >> 2, u = idx & 3;
            *(uint4*)&Bs[row * 32 + (u ^ (row & 3)) * 8] =
                *(const uint4*)&W1t[(size_t)(tN + row) * 256 + k0 + u * 8];
        }
        __syncthreads();

        bfrag af[4], bfv[8];
#pragma unroll
        for (int mm = 0; mm < 4; mm++) {
            int row = wm * 64 + mm * 16 + lr;
            af[mm] = *(const bfrag*)&As[row * 32 + (lg ^ (row & 3)) * 8];
        }
#pragma unroll
        for (int nn = 0; nn < 8; nn++) {
            int row = wn * 128 + nn * 16 + lr;
            bfv[nn] = *(const bfrag*)&Bs[row * 32 + (lg ^ (row & 3)) * 8];
        }
#pragma unroll
        for (int mm = 0; mm < 4; mm++)
#pragma unroll
            for (int nn = 0; nn < 8; nn++)
                acc[mm][nn] = __builtin_amdgcn_mfma_f32_16x16x32_bf16(af[mm], bfv[nn], acc[mm][nn], 0, 0, 0);
        __syncthreads();
    }

    if (bx == 0) {
#pragma unroll
        for (int mm = 0; mm < 4; mm++)
#pragma unroll
            for (int nn = 0; nn < 8; nn++)
#pragma unroll
                for (int r = 0; r < 4; r++) {
                    int row = tM + wm * 64 + mm * 16 + lg * 4 + r;
                    int col = wn * 128 + nn * 16 + lr;
                    YJ[(size_t)row * 256 + col] = f2bf(acc[mm][nn][r] + bias1[col]);
                }
    } else {
#pragma unroll
        for (int mm = 0; mm < 4; mm++) {
#pragma unroll
            for (int r = 0; r < 4; r++) {
                int row = tM + wm * 64 + mm * 16 + lg * 4 + r;
                int c = colof[row];
                float s = valof[row];
#pragma unroll
                for (int nn = 0; nn < 8; nn++) {
                    int col = wn * 128 + nn * 16 + lr;
                    float v = acc[mm][nn][r] + bias1[256 + col]
                            + s * bf2f(XW[(size_t)c * 256 + col]);
                    UIb[(size_t)row * 256 + col] = f2bf(v);
                }
            }
        }
    }
}

// ---------------------------------------------------------------------------
// Gather layer 0 (up-map pre-composed into edges):
//   X1[d] = ui0_b + valof[d]*XNI[colof[d]] + sumA[d]*uj0_b + sum vals0*XNJ[srcs0]
// ---------------------------------------------------------------------------
__global__ __launch_bounds__(256)
void gather0_kernel(const int* __restrict__ offs, const int* __restrict__ cnt,
                    const int* __restrict__ srcs0, const float* __restrict__ vals0,
                    const int* __restrict__ colof, const float* __restrict__ valof,
                    const float* __restrict__ sumA,
                    const ushort* __restrict__ XNJ, const ushort* __restrict__ XNI,
                    const float* __restrict__ ui_b, const float* __restrict__ uj_b,
                    ushort* __restrict__ X1)
{
    int d = blockIdx.x * 4 + (threadIdx.x >> 6);
    int f = (threadIdx.x & 63) * 4;
    int c = colof[d];
    float s = valof[d];
    float sA = sumA[d];
    ushort4 u = *(const ushort4*)&XNI[(size_t)c * 256 + f];
    const ushort* up = (const ushort*)&u;
    float a0 = ui_b[f + 0] + sA * uj_b[f + 0] + s * bf2f(up[0]);
    float a1 = ui_b[f + 1] + sA * uj_b[f + 1] + s * bf2f(up[1]);
    float a2 = ui_b[f + 2] + sA * uj_b[f + 2] + s * bf2f(up[2]);
    float a3 = ui_b[f + 3] + sA * uj_b[f + 3] + s * bf2f(up[3]);

    int st = offs[d], n = cnt[d];
    if (n > 0) {
        int   sc = srcs0[st];
        float ac = vals0[st];
        ushort4 vc = *(const ushort4*)&XNJ[(size_t)sc * 256 + f];
        for (int e = 1; e < n; e++) {
            int   sn = srcs0[st + e];
            float an = vals0[st + e];
            ushort4 vn = *(const ushort4*)&XNJ[(size_t)sn * 256 + f];
            const ushort* vp = (const ushort*)&vc;
            a0 += ac * bf2f(vp[0]); a1 += ac * bf2f(vp[1]);
            a2 += ac * bf2f(vp[2]); a3 += ac * bf2f(vp[3]);
            vc = vn; ac = an;
        }
        const ushort* vp = (const ushort*)&vc;
        a0 += ac * bf2f(vp[0]); a1 += ac * bf2f(vp[1]);
        a2 += ac * bf2f(vp[2]); a3 += ac * bf2f(vp[3]);
    }
    *(ushort4*)&X1[(size_t)d * 256 + f] =
        make_ushort4(f2bf(a0), f2bf(a1), f2bf(a2), f2bf(a3));
}

// ---------------------------------------------------------------------------
// Gather layer 1: out[d] = bf2f(UIb[d]) + sum valsA*YJ[srcsA]   (single write)
// ---------------------------------------------------------------------------
__global__ __launch_bounds__(256)
void gather1_kernel(const int* __restrict__ offs, const int* __restrict__ cnt,
                    const int* __restrict__ srcsA, const float* __restrict__ valsA,
                    const ushort* __restrict__ YJ, const ushort* __restrict__ UIb,
                    float* __restrict__ out)
{
    int d = blockIdx.x * 4 + (threadIdx.x >> 6);
    int f = (threadIdx.x & 63) * 4;
    ushort4 b4 = *(const ushort4*)&UIb[(size_t)d * 256 + f];
    const ushort* bp = (const ushort*)&b4;
    float a0 = bf2f(bp[0]), a1 = bf2f(bp[1]), a2 = bf2f(bp[2]), a3 = bf2f(bp[3]);

    int st = offs[d], n = cnt[d];
    if (n > 0) {
        int   sc = srcsA[st];
        float ac = valsA[st];
        ushort4 vc = *(const ushort4*)&YJ[(size_t)sc * 256 + f];
        for (int e = 1; e < n; e++) {
            int   sn = srcsA[st + e];
            float an = valsA[st + e];
            ushort4 vn = *(const ushort4*)&YJ[(size_t)sn * 256 + f];
            const ushort* vp = (const ushort*)&vc;
            a0 += ac * bf2f(vp[0]); a1 += ac * bf2f(vp[1]);
            a2 += ac * bf2f(vp[2]); a3 += ac * bf2f(vp[3]);
            vc = vn; ac = an;
        }
        const ushort* vp = (const ushort*)&vc;
        a0 += ac * bf2f(vp[0]); a1 += ac * bf2f(vp[1]);
        a2 += ac * bf2f(vp[2]); a3 += ac * bf2f(vp[3]);
    }
    *(float4*)&out[(size_t)d * 256 + f] = make_float4(a0, a1, a2, a3);
}

// ---------------------------------------------------------------------------
// Host launcher
// ---------------------------------------------------------------------------
extern "C" void kernel_launch(void* const* d_in, const int* in_sizes, int n_in,
                              void* d_out, int out_size, void* d_ws, size_t ws_size,
                              hipStream_t stream)
{
    const float* x      = (const float*)d_in[0];
    const int*   up_row = (const int*)  d_in[1];
    const int*   up_col = (const int*)  d_in[2];
    const float* up_val = (const float*)d_in[3];
    const int*   e_src  = (const int*)  d_in[4];
    const int*   e_dst  = (const int*)  d_in[5];
    const float* adjv   = (const float*)d_in[6];
    const float* W_res  = (const float*)d_in[7];
    const float* b_res  = (const float*)d_in[8];
    const float* bn0_g  = (const float*)d_in[9];
    const float* bn0_b  = (const float*)d_in[10];
    const float* bn1_g  = (const float*)d_in[11];
    const float* bn1_b  = (const float*)d_in[12];
    const float* Ui0_W  = (const float*)d_in[13];
    const float* Ui0_b  = (const float*)d_in[14];
    const float* Uj0_W  = (const float*)d_in[15];
    const float* Uj0_b  = (const float*)d_in[16];
    const float* Ui1_W  = (const float*)d_in[17];
    const float* Ui1_b  = (const float*)d_in[18];
    const float* Uj1_W  = (const float*)d_in[19];
    const float* Uj1_b  = (const float*)d_in[20];

    float* out = (float*)d_out;

    // ---- workspace layout ----
    char* ws = (char*)d_ws;
    size_t off = 0;
    auto alloc = [&](size_t bytes) -> char* {
        char* p = ws + off;
        off = (off + bytes + 255) & ~(size_t)255;
        return p;
    };
    ushort* XW    = (ushort*)alloc((size_t)V_PREV * F_OUT * 2);   // 8.4 MB
    ushort* XNJ   = (ushort*)alloc((size_t)V_PREV * F_OUT * 2);   // 8.4 MB (hot table)
    ushort* XNI   = (ushort*)alloc((size_t)V_PREV * F_OUT * 2);   // 8.4 MB
    ushort* X1    = (ushort*)alloc((size_t)V_NEXT * F_OUT * 2);   // 33.6 MB (H1 in place)
    ushort* YJ    = (ushort*)alloc((size_t)V_NEXT * F_OUT * 2);   // 33.6 MB
    ushort* UIb   = (ushort*)alloc((size_t)V_NEXT * F_OUT * 2);   // 33.6 MB
    int*    cnt   = (int*)   alloc(V_NEXT * 4);
    float*  sumA  = (float*) alloc(V_NEXT * 4);
    int*    offs  = (int*)   alloc(V_NEXT * 4);
    int*    cursor= (int*)   alloc(V_NEXT * 4);
    int*    bsum  = (int*)   alloc(256 * 4);
    int*    boff  = (int*)   alloc(256 * 4);
    int*    srcsA = (int*)   alloc((size_t)N_EDGE * 4);
    float*  valsA = (float*) alloc((size_t)N_EDGE * 4);
    int*    srcs0 = (int*)   alloc((size_t)N_EDGE * 4);
    float*  vals0 = (float*) alloc((size_t)N_EDGE * 4);
    int*    colof = (int*)   alloc(V_NEXT * 4);
    float*  valof = (float*) alloc(V_NEXT * 4);
    ushort* WresT = (ushort*)alloc(256 * 512 * 2);
    ushort* W0t   = (ushort*)alloc(512 * 512 * 2);
    ushort* W1t   = (ushort*)alloc(512 * 256 * 2);
    float*  bias1 = (float*) alloc(512 * 4);
    float*  psum0 = (float*) alloc(128 * 512 * 4);
    float*  psq0  = (float*) alloc(128 * 512 * 4);
    float*  sc0   = (float*) alloc(512 * 4);
    float*  sh0   = (float*) alloc(512 * 4);
    float*  psum1 = (float*) alloc(512 * 256 * 4);
    float*  psq1  = (float*) alloc(512 * 256 * 4);
    float*  sc1   = (float*) alloc(256 * 4);
    float*  sh1   = (float*) alloc(256 * 4);
    (void)ws_size; (void)in_sizes; (void)n_in; (void)out_size;

    // ---- prep + CSR build (independent of x) ----
    prep_weights_kernel<<<1024, 256, 0, stream>>>(W_res, Ui0_W, Uj0_W, Ui1_W, Uj1_W,
                                                  Ui1_b, Uj1_b, b_res,
                                                  WresT, W0t, W1t, bias1);
    invert_up_kernel<<<NNZ_UP / 256, 256, 0, stream>>>(up_row, up_col, up_val, colof, valof);
    hipMemsetAsync(cnt,  0, (size_t)V_NEXT * 4, stream);
    hipMemsetAsync(sumA, 0, (size_t)V_NEXT * 4, stream);
    hist_kernel<<<N_EDGE / 256, 256, 0, stream>>>(e_dst, adjv, cnt, sumA);
    scan_block_kernel<<<256, 256, 0, stream>>>(cnt, offs, bsum);
    scan_top_kernel<<<1, 256, 0, stream>>>(bsum, boff);
    add_offs_kernel<<<256, 256, 0, stream>>>(offs, boff, cursor);
    fill_kernel<<<N_EDGE / 256, 256, 0, stream>>>(e_src, e_dst, adjv, colof, valof,
                                                  cursor, srcsA, valsA, srcs0, vals0);

    // ---- bn0 stats ----
    bn0_part_kernel<<<128, 256, 0, stream>>>(x, psum0, psq0);
    bn_finish_kernel<<<128, 256, 0, stream>>>(psum0, psq0, 128, 512, 1.0f / V_PREV,
                                              bn0_g, bn0_b, sc0, sh0);

    // ---- GEMM0 (fused bn0+relu+cast): XW, XNJ, XNI [16384,256] each ----
    gemm0_fused_kernel<<<dim3(6, 128), 256, 0, stream>>>(x, WresT, W0t, sc0, sh0,
                                                         XW, XNJ, XNI);

    // ---- ECC layer 0 aggregation (up map pre-composed) ----
    gather0_kernel<<<V_NEXT / 4, 256, 0, stream>>>(offs, cnt, srcs0, vals0,
                                                   colof, valof, sumA,
                                                   XNJ, XNI, Ui0_b, Uj0_b, X1);

    // ---- bn1 stats + in-place apply ----
    bn1_part_bf16_kernel<<<512, 256, 0, stream>>>(X1, psum1, psq1);
    bn_finish_kernel<<<64, 256, 0, stream>>>(psum1, psq1, 512, 256, 1.0f / V_NEXT,
                                             bn1_g, bn1_b, sc1, sh1);
    bn1_apply_kernel<<<16384, 256, 0, stream>>>(X1, sc1, sh1);

    // ---- GEMM1 clean: YJ + UIb ----
    gemm1_clean_kernel<<<dim3(2, 512), 256, 0, stream>>>(X1, W1t, bias1,
                                                         colof, valof, XW, YJ, UIb);

    // ---- ECC layer 1 aggregation -> out ----
    gather1_kernel<<<V_NEXT / 4, 256, 0, stream>>>(offs, cnt, srcsA, valsA, YJ, UIb, out);
}

// Round 7
// 296.291 us; speedup vs baseline: 1.0827x; 1.0827x over previous
//
#include <hip/hip_runtime.h>

// ---------------------------------------------------------------------------
// Problem constants
// ---------------------------------------------------------------------------
#define V_PREV 16384
#define V_NEXT 65536
#define F_IN   512
#define F_OUT  256
#define NNZ_UP 65536
#define N_EDGE 524288

using f32x4 = __attribute__((ext_vector_type(4))) float;
using bfrag = __attribute__((ext_vector_type(8))) short;   // 8 x bf16

__device__ __forceinline__ ushort f2bf(float f) {
    union { float f; unsigned u; } v; v.f = f;
    unsigned r = (v.u + 0x7FFFu + ((v.u >> 16) & 1u)) >> 16;
    return (ushort)r;
}
__device__ __forceinline__ float bf2f(ushort h) {
    union { unsigned u; float f; } v; v.u = ((unsigned)h) << 16; return v.f;
}

// ---------------------------------------------------------------------------
// Weight prep:
//   WresT [256][512] = W_res^T
//   W0t   [512][512] = [Uj0 | Ui0]^T
//   W1cat [256][512] : k<256 -> Ui1^T, k>=256 -> Uj1^T   (for [H1|G] @ .)
//   biasUi[256] = Ui1_b + b_res
// ---------------------------------------------------------------------------
__global__ void prep_weights_kernel(const float* __restrict__ Wres,
                                    const float* __restrict__ Ui0W, const float* __restrict__ Uj0W,
                                    const float* __restrict__ Ui1W, const float* __restrict__ Uj1W,
                                    const float* __restrict__ Ui1b, const float* __restrict__ bres,
                                    ushort* __restrict__ WresT, ushort* __restrict__ W0t,
                                    ushort* __restrict__ W1cat, float* __restrict__ biasUi)
{
    int i = blockIdx.x * blockDim.x + threadIdx.x;   // 0 .. 512*512-1
    if (i < 256 * 512) {
        int n = i / 512, k = i % 512;
        WresT[i] = f2bf(Wres[k * 256 + n]);
        W1cat[i] = f2bf(k < 256 ? Ui1W[k * 256 + n] : Uj1W[(k - 256) * 256 + n]);
    }
    if (i < 512 * 512) {
        int n = i / 512, k = i % 512;
        W0t[i] = f2bf(n < 256 ? Uj0W[k * 256 + n] : Ui0W[k * 256 + (n - 256)]);
    }
    if (i < 256) biasUi[i] = Ui1b[i] + bres[i];
}

// ---------------------------------------------------------------------------
// Up-map invert + CSR build
// ---------------------------------------------------------------------------
__global__ void invert_up_kernel(const int* __restrict__ up_row, const int* __restrict__ up_col,
                                 const float* __restrict__ up_val,
                                 int* __restrict__ colof, float* __restrict__ valof)
{
    int k = blockIdx.x * blockDim.x + threadIdx.x;
    int r = up_row[k];
    colof[r] = up_col[k];
    valof[r] = up_val[k];
}

__global__ void hist_kernel(const int* __restrict__ dst, const float* __restrict__ adjv,
                            int* __restrict__ cnt, float* __restrict__ sumA)
{
    int e = blockIdx.x * blockDim.x + threadIdx.x;
    int d = dst[e];
    atomicAdd(&cnt[d], 1);
    atomicAdd(&sumA[d], adjv[e]);
}

__global__ void scan_block_kernel(const int* __restrict__ cnt, int* __restrict__ offs,
                                  int* __restrict__ bsum)
{
    __shared__ int buf[2][256];
    int t = threadIdx.x;
    int i = blockIdx.x * 256 + t;
    int v = cnt[i];
    int p = 0;
    buf[0][t] = v;
    __syncthreads();
    for (int d = 1; d < 256; d <<= 1) {
        int nv = buf[p][t] + ((t >= d) ? buf[p][t - d] : 0);
        buf[p ^ 1][t] = nv;
        p ^= 1;
        __syncthreads();
    }
    int incl = buf[p][t];
    offs[i] = incl - v;
    if (t == 255) bsum[blockIdx.x] = incl;
}

__global__ void scan_top_kernel(const int* __restrict__ bsum, int* __restrict__ boff)
{
    __shared__ int buf[2][256];
    int t = threadIdx.x;
    int v = bsum[t];
    int p = 0;
    buf[0][t] = v;
    __syncthreads();
    for (int d = 1; d < 256; d <<= 1) {
        int nv = buf[p][t] + ((t >= d) ? buf[p][t - d] : 0);
        buf[p ^ 1][t] = nv;
        p ^= 1;
        __syncthreads();
    }
    boff[t] = buf[p][t] - v;
}

__global__ void add_offs_kernel(int* __restrict__ offs, const int* __restrict__ boff,
                                int* __restrict__ cursor)
{
    int i = blockIdx.x * 256 + threadIdx.x;
    int o = offs[i] + boff[blockIdx.x];
    offs[i] = o;
    cursor[i] = o;
}

// dst-sorted edges; layer-0 variant pre-composes the up map
__global__ void fill_kernel(const int* __restrict__ src, const int* __restrict__ dst,
                            const float* __restrict__ adjv,
                            const int* __restrict__ colof, const float* __restrict__ valof,
                            int* __restrict__ cursor,
                            int* __restrict__ srcsA, float* __restrict__ valsA,
                            int* __restrict__ srcs0, float* __restrict__ vals0)
{
    int e = blockIdx.x * blockDim.x + threadIdx.x;
    int d = dst[e];
    int s = src[e];
    float a = adjv[e];
    int p = atomicAdd(&cursor[d], 1);
    srcsA[p] = s;
    valsA[p] = a;
    srcs0[p] = colof[s];
    vals0[p] = a * valof[s];
}

// ---------------------------------------------------------------------------
// BatchNorm stats
// ---------------------------------------------------------------------------
__global__ void bn0_part_kernel(const float* __restrict__ x,
                                float* __restrict__ psum, float* __restrict__ psq)
{
    int blk = blockIdx.x, t = threadIdx.x;
    float s0 = 0, s1 = 0, q0 = 0, q1 = 0;
    for (int r = 0; r < 128; r++) {
        size_t base = ((size_t)blk * 128 + r) * 512;
        float a = x[base + t], b = x[base + t + 256];
        s0 += a; q0 += a * a; s1 += b; q1 += b * b;
    }
    psum[blk * 512 + t] = s0; psum[blk * 512 + t + 256] = s1;
    psq [blk * 512 + t] = q0; psq [blk * 512 + t + 256] = q1;
}

__global__ void bn1_part_bf16_kernel(const ushort* __restrict__ xx,
                                     float* __restrict__ psum, float* __restrict__ psq)
{
    int blk = blockIdx.x, t = threadIdx.x;
    float s = 0, q = 0;
    for (int r = 0; r < 128; r++) {
        float a = bf2f(xx[((size_t)blk * 128 + r) * 256 + t]);
        s += a; q += a * a;
    }
    psum[blk * 256 + t] = s; psq[blk * 256 + t] = q;
}

// Parallel finish: one wave per channel; produces sc = g*rstd, sh = b - mean*sc
__global__ void bn_finish_kernel(const float* __restrict__ psum, const float* __restrict__ psq,
                                 int nblocks, int C, float invN,
                                 const float* __restrict__ g, const float* __restrict__ b,
                                 float* __restrict__ sc, float* __restrict__ sh)
{
    int gw = (blockIdx.x * blockDim.x + threadIdx.x) >> 6;   // channel
    int lane = threadIdx.x & 63;
    if (gw >= C) return;
    float s = 0, q = 0;
    for (int i = lane; i < nblocks; i += 64) {
        s += psum[(size_t)i * C + gw];
        q += psq [(size_t)i * C + gw];
    }
#pragma unroll
    for (int d = 32; d > 0; d >>= 1) {
        s += __shfl_xor(s, d);
        q += __shfl_xor(q, d);
    }
    if (lane == 0) {
        float m = s * invN;
        float v = q * invN - m * m;
        float r = rsqrtf(v + 1e-5f);
        float scale = r * g[gw];
        sc[gw] = scale;
        sh[gw] = b[gw] - m * scale;
    }
}

// ---------------------------------------------------------------------------
// GEMM0 fused: reads x f32 [16384,512] directly. 1D grid 768, XCD-grouped:
// the 6 N-tiles sharing one 128-row A slab land on the SAME XCD (id mod 8).
//   bx 0,1: XW  = bf16(x) @ WresT^T
//   bx 2,3: XNJ = relu(bn0(x)) @ Uj0
//   bx 4,5: XNI = relu(bn0(x)) @ Ui0
// LDS linear [row][32 units] + XOR unit^(row&3): conflict-free write+read.
// ---------------------------------------------------------------------------
__global__ __launch_bounds__(256)
void gemm0_fused_kernel(const float* __restrict__ x,
                        const ushort* __restrict__ WresT, const ushort* __restrict__ W0t,
                        const float* __restrict__ sc0, const float* __restrict__ sh0,
                        ushort* __restrict__ XW, ushort* __restrict__ XNJ,
                        ushort* __restrict__ XNI)
{
    __shared__ ushort As[128 * 32];
    __shared__ ushort Bs[128 * 32];
    __shared__ float s_sc[512], s_sh[512];

    const int tid = threadIdx.x;
    // swizzle: id = xcd + 8*(slot*6 + j), by = slot*8 + xcd, bx = j
    const int id   = blockIdx.x;
    const int xcd  = id & 7;
    const int rest = id >> 3;          // 0..95
    const int slot = rest / 6;         // 0..15
    const int bx   = rest - slot * 6;  // 0..5
    const int by   = slot * 8 + xcd;   // 0..127

    const bool bnmode = bx >= 2;
    const ushort* Bt = bnmode ? W0t : WresT;
    const int btrow = bnmode ? (bx - 2) * 128 : bx * 128;
    ushort* Cout = (bx < 2) ? XW : (bx < 4 ? XNJ : XNI);
    const int colbase = (bx & 1) * 128;
    const int tM = by * 128;

    for (int i = tid; i < 512; i += 256) { s_sc[i] = sc0[i]; s_sh[i] = sh0[i]; }
    __syncthreads();

    const int lane = tid & 63;
    const int wave = tid >> 6;
    const int wm = wave >> 1, wn = wave & 1;
    const int lr = lane & 15, lg = lane >> 4;

    const int ra = tid >> 1;            // A row 0..127
    const int ua = (tid & 1) * 2;       // first of two 16B units
    const int rb = tid >> 2;            // B fill row
    const int ub = tid & 3;

    f32x4 acc[4][4] = {};

    for (int k0 = 0; k0 < 512; k0 += 32) {
        const float* xp = &x[(size_t)(tM + ra) * 512 + k0 + ua * 8];
        float4 f0 = *(const float4*)(xp);
        float4 f1 = *(const float4*)(xp + 4);
        float4 f2 = *(const float4*)(xp + 8);
        float4 f3 = *(const float4*)(xp + 12);
        float vv[16] = { f0.x,f0.y,f0.z,f0.w, f1.x,f1.y,f1.z,f1.w,
                         f2.x,f2.y,f2.z,f2.w, f3.x,f3.y,f3.z,f3.w };
        ushort hh[16];
        if (bnmode) {
#pragma unroll
            for (int j = 0; j < 16; j++) {
                int c = k0 + ua * 8 + j;
                hh[j] = f2bf(fmaxf(vv[j] * s_sc[c] + s_sh[c], 0.0f));
            }
        } else {
#pragma unroll
            for (int j = 0; j < 16; j++) hh[j] = f2bf(vv[j]);
        }
        *(uint4*)&As[ra * 32 + ((ua    ) ^ (ra & 3)) * 8] = *(uint4*)&hh[0];
        *(uint4*)&As[ra * 32 + ((ua + 1) ^ (ra & 3)) * 8] = *(uint4*)&hh[8];

#pragma unroll
        for (int i = 0; i < 2; i++) {
            int row = rb + i * 64;
            *(uint4*)&Bs[row * 32 + (ub ^ (row & 3)) * 8] =
                *(const uint4*)&Bt[(size_t)(btrow + row) * 512 + k0 + ub * 8];
        }
        __syncthreads();

        bfrag af[4], bfv[4];
#pragma unroll
        for (int mm = 0; mm < 4; mm++) {
            int row = wm * 64 + mm * 16 + lr;
            af[mm] = *(const bfrag*)&As[row * 32 + (lg ^ (row & 3)) * 8];
        }
#pragma unroll
        for (int nn = 0; nn < 4; nn++) {
            int row = wn * 64 + nn * 16 + lr;
            bfv[nn] = *(const bfrag*)&Bs[row * 32 + (lg ^ (row & 3)) * 8];
        }
#pragma unroll
        for (int mm = 0; mm < 4; mm++)
#pragma unroll
            for (int nn = 0; nn < 4; nn++)
                acc[mm][nn] = __builtin_amdgcn_mfma_f32_16x16x32_bf16(af[mm], bfv[nn], acc[mm][nn], 0, 0, 0);
        __syncthreads();
    }

#pragma unroll
    for (int mm = 0; mm < 4; mm++)
#pragma unroll
        for (int nn = 0; nn < 4; nn++)
#pragma unroll
            for (int r = 0; r < 4; r++) {
                int row = tM + wm * 64 + mm * 16 + lg * 4 + r;
                int col = colbase + wn * 64 + nn * 16 + lr;
                Cout[(size_t)row * 256 + col] = f2bf(acc[mm][nn][r]);
            }
}

// ---------------------------------------------------------------------------
// Gather layer 0 (up-map pre-composed into edges):
//   X1[d] = ui0_b + valof[d]*XNI[colof[d]] + sumA[d]*uj0_b + sum vals0*XNJ[srcs0]
// ---------------------------------------------------------------------------
__global__ __launch_bounds__(256)
void gather0_kernel(const int* __restrict__ offs, const int* __restrict__ cnt,
                    const int* __restrict__ srcs0, const float* __restrict__ vals0,
                    const int* __restrict__ colof, const float* __restrict__ valof,
                    const float* __restrict__ sumA,
                    const ushort* __restrict__ XNJ, const ushort* __restrict__ XNI,
                    const float* __restrict__ ui_b, const float* __restrict__ uj_b,
                    ushort* __restrict__ X1)
{
    int d = blockIdx.x * 4 + (threadIdx.x >> 6);
    int f = (threadIdx.x & 63) * 4;
    int c = colof[d];
    float s = valof[d];
    float sA = sumA[d];
    ushort4 u = *(const ushort4*)&XNI[(size_t)c * 256 + f];
    const ushort* up = (const ushort*)&u;
    float a0 = ui_b[f + 0] + sA * uj_b[f + 0] + s * bf2f(up[0]);
    float a1 = ui_b[f + 1] + sA * uj_b[f + 1] + s * bf2f(up[1]);
    float a2 = ui_b[f + 2] + sA * uj_b[f + 2] + s * bf2f(up[2]);
    float a3 = ui_b[f + 3] + sA * uj_b[f + 3] + s * bf2f(up[3]);

    int st = offs[d], n = cnt[d];
    if (n > 0) {
        int   sc = srcs0[st];
        float ac = vals0[st];
        ushort4 vc = *(const ushort4*)&XNJ[(size_t)sc * 256 + f];
        for (int e = 1; e < n; e++) {
            int   sn = srcs0[st + e];
            float an = vals0[st + e];
            ushort4 vn = *(const ushort4*)&XNJ[(size_t)sn * 256 + f];
            const ushort* vp = (const ushort*)&vc;
            a0 += ac * bf2f(vp[0]); a1 += ac * bf2f(vp[1]);
            a2 += ac * bf2f(vp[2]); a3 += ac * bf2f(vp[3]);
            vc = vn; ac = an;
        }
        const ushort* vp = (const ushort*)&vc;
        a0 += ac * bf2f(vp[0]); a1 += ac * bf2f(vp[1]);
        a2 += ac * bf2f(vp[2]); a3 += ac * bf2f(vp[3]);
    }
    *(ushort4*)&X1[(size_t)d * 256 + f] =
        make_ushort4(f2bf(a0), f2bf(a1), f2bf(a2), f2bf(a3));
}

// ---------------------------------------------------------------------------
// Gather layer 1 (pre-GEMM, bn1+relu folded):
//   G[d] = sum_e valsA * relu(sc1*X1[srcsA] + sh1)     (bf16 out)
// ---------------------------------------------------------------------------
__global__ __launch_bounds__(256)
void gather1G_kernel(const int* __restrict__ offs, const int* __restrict__ cnt,
                     const int* __restrict__ srcsA, const float* __restrict__ valsA,
                     const ushort* __restrict__ X1,
                     const float* __restrict__ sc1, const float* __restrict__ sh1,
                     ushort* __restrict__ G)
{
    int d = blockIdx.x * 4 + (threadIdx.x >> 6);
    int f = (threadIdx.x & 63) * 4;
    float4 sc = *(const float4*)&sc1[f];
    float4 sh = *(const float4*)&sh1[f];
    float a0 = 0, a1 = 0, a2 = 0, a3 = 0;

    int st = offs[d], n = cnt[d];
    if (n > 0) {
        int   s0 = srcsA[st];
        float ac = valsA[st];
        ushort4 vc = *(const ushort4*)&X1[(size_t)s0 * 256 + f];
        for (int e = 1; e < n; e++) {
            int   sn = srcsA[st + e];
            float an = valsA[st + e];
            ushort4 vn = *(const ushort4*)&X1[(size_t)sn * 256 + f];
            const ushort* vp = (const ushort*)&vc;
            a0 += ac * fmaxf(bf2f(vp[0]) * sc.x + sh.x, 0.0f);
            a1 += ac * fmaxf(bf2f(vp[1]) * sc.y + sh.y, 0.0f);
            a2 += ac * fmaxf(bf2f(vp[2]) * sc.z + sh.z, 0.0f);
            a3 += ac * fmaxf(bf2f(vp[3]) * sc.w + sh.w, 0.0f);
            vc = vn; ac = an;
        }
        const ushort* vp = (const ushort*)&vc;
        a0 += ac * fmaxf(bf2f(vp[0]) * sc.x + sh.x, 0.0f);
        a1 += ac * fmaxf(bf2f(vp[1]) * sc.y + sh.y, 0.0f);
        a2 += ac * fmaxf(bf2f(vp[2]) * sc.z + sh.z, 0.0f);
        a3 += ac * fmaxf(bf2f(vp[3]) * sc.w + sh.w, 0.0f);
    }
    *(ushort4*)&G[(size_t)d * 256 + f] =
        make_ushort4(f2bf(a0), f2bf(a1), f2bf(a2), f2bf(a3));
}

// ---------------------------------------------------------------------------
// GEMM final: out[65536,256] f32 = [relu(bn1(X1)) | G] @ W1cat^T + biases + res
//   A row (K=512): k<256 -> bn+relu(X1[row,k]); k>=256 -> G[row,k-256]
//   epilogue: + biasUi[col] + sumA[row]*Uj1_b[col] + valof[row]*XW[colof[row],col]
// grid 512 x 256thr; 128 M-rows x 256 N per block; BK=32; LDS 26KB.
// ---------------------------------------------------------------------------
__global__ __launch_bounds__(256, 2)
void gemm_final_kernel(const ushort* __restrict__ X1, const ushort* __restrict__ G,
                       const ushort* __restrict__ W1cat,
                       const float* __restrict__ sc1, const float* __restrict__ sh1,
                       const float* __restrict__ biasUi, const float* __restrict__ uj1_b,
                       const float* __restrict__ sumA,
                       const int* __restrict__ colof, const float* __restrict__ valof,
                       const ushort* __restrict__ XW,
                       float* __restrict__ out)
{
    __shared__ ushort As[128 * 32];
    __shared__ ushort Bs[256 * 32];
    __shared__ float s_sc[256], s_sh[256];

    const int tid = threadIdx.x;
    const int tM = blockIdx.x * 128;

    s_sc[tid] = sc1[tid]; s_sh[tid] = sh1[tid];
    __syncthreads();

    const int lane = tid & 63;
    const int wave = tid >> 6;
    const int wm = wave >> 1, wn = wave & 1;    // wave tile 64 rows x 128 cols
    const int lr = lane & 15, lg = lane >> 4;

    const int rstg = tid >> 2;      // 0..63 (A: +0/+64; B: x4)
    const int ustg = tid & 3;

    f32x4 acc[4][8] = {};

    for (int k0 = 0; k0 < 512; k0 += 32) {
        // --- A stage: 128 rows x 4 units, 2 per thread ---
#pragma unroll
        for (int i = 0; i < 2; i++) {
            int row = rstg + i * 64;
            ushort h[8];
            if (k0 < 256) {
                *(uint4*)h = *(const uint4*)&X1[(size_t)(tM + row) * 256 + k0 + ustg * 8];
#pragma unroll
                for (int j = 0; j < 8; j++) {
                    int c = k0 + ustg * 8 + j;
                    h[j] = f2bf(fmaxf(bf2f(h[j]) * s_sc[c] + s_sh[c], 0.0f));
                }
            } else {
                *(uint4*)h = *(const uint4*)&G[(size_t)(tM + row) * 256 + (k0 - 256) + ustg * 8];
            }
            *(uint4*)&As[row * 32 + (ustg ^ (row & 3)) * 8] = *(uint4*)h;
        }
        // --- B stage: 256 rows x 4 units, 4 per thread ---
#pragma unroll
        for (int i = 0; i < 4; i++) {
            int row = rstg + i * 64;
            *(uint4*)&Bs[row * 32 + (ustg ^ (row & 3)) * 8] =
                *(const uint4*)&W1cat[(size_t)row * 512 + k0 + ustg * 8];
        }
        __syncthreads();

        bfrag af[4], bfv[8];
#pragma unroll
        for (int mm = 0; mm < 4; mm++) {
            int row = wm * 64 + mm * 16 + lr;
            af[mm] = *(const bfrag*)&As[row * 32 + (lg ^ (row & 3)) * 8];
        }
#pragma unroll
        for (int nn = 0; nn < 8; nn++) {
            int row = wn * 128 + nn * 16 + lr;
            bfv[nn] = *(const bfrag*)&Bs[row * 32 + (lg ^ (row & 3)) * 8];
        }
#pragma unroll
        for (int mm = 0; mm < 4; mm++)
#pragma unroll
            for (int nn = 0; nn < 8; nn++)
                acc[mm][nn] = __builtin_amdgcn_mfma_f32_16x16x32_bf16(af[mm], bfv[nn], acc[mm][nn], 0, 0, 0);
        __syncthreads();
    }

    // epilogue
    float bUi[8], bUj[8];
#pragma unroll
    for (int nn = 0; nn < 8; nn++) {
        int col = wn * 128 + nn * 16 + lr;
        bUi[nn] = biasUi[col];
        bUj[nn] = uj1_b[col];
    }
#pragma unroll
    for (int mm = 0; mm < 4; mm++) {
#pragma unroll
        for (int r = 0; r < 4; r++) {
            int row = tM + wm * 64 + mm * 16 + lg * 4 + r;
            int c = colof[row];
            float s = valof[row];
            float sA = sumA[row];
#pragma unroll
            for (int nn = 0; nn < 8; nn++) {
                int col = wn * 128 + nn * 16 + lr;
                float v = acc[mm][nn][r] + bUi[nn] + sA * bUj[nn]
                        + s * bf2f(XW[(size_t)c * 256 + col]);
                out[(size_t)row * 256 + col] = v;
            }
        }
    }
}

// ---------------------------------------------------------------------------
// Host launcher
// ---------------------------------------------------------------------------
extern "C" void kernel_launch(void* const* d_in, const int* in_sizes, int n_in,
                              void* d_out, int out_size, void* d_ws, size_t ws_size,
                              hipStream_t stream)
{
    const float* x      = (const float*)d_in[0];
    const int*   up_row = (const int*)  d_in[1];
    const int*   up_col = (const int*)  d_in[2];
    const float* up_val = (const float*)d_in[3];
    const int*   e_src  = (const int*)  d_in[4];
    const int*   e_dst  = (const int*)  d_in[5];
    const float* adjv   = (const float*)d_in[6];
    const float* W_res  = (const float*)d_in[7];
    const float* b_res  = (const float*)d_in[8];
    const float* bn0_g  = (const float*)d_in[9];
    const float* bn0_b  = (const float*)d_in[10];
    const float* bn1_g  = (const float*)d_in[11];
    const float* bn1_b  = (const float*)d_in[12];
    const float* Ui0_W  = (const float*)d_in[13];
    const float* Ui0_b  = (const float*)d_in[14];
    const float* Uj0_W  = (const float*)d_in[15];
    const float* Uj0_b  = (const float*)d_in[16];
    const float* Ui1_W  = (const float*)d_in[17];
    const float* Ui1_b  = (const float*)d_in[18];
    const float* Uj1_W  = (const float*)d_in[19];
    const float* Uj1_b  = (const float*)d_in[20];

    float* out = (float*)d_out;

    // ---- workspace layout ----
    char* ws = (char*)d_ws;
    size_t off = 0;
    auto alloc = [&](size_t bytes) -> char* {
        char* p = ws + off;
        off = (off + bytes + 255) & ~(size_t)255;
        return p;
    };
    ushort* XW    = (ushort*)alloc((size_t)V_PREV * F_OUT * 2);   // 8.4 MB
    ushort* XNJ   = (ushort*)alloc((size_t)V_PREV * F_OUT * 2);   // 8.4 MB
    ushort* XNI   = (ushort*)alloc((size_t)V_PREV * F_OUT * 2);   // 8.4 MB
    ushort* X1    = (ushort*)alloc((size_t)V_NEXT * F_OUT * 2);   // 33.6 MB
    ushort* G     = (ushort*)alloc((size_t)V_NEXT * F_OUT * 2);   // 33.6 MB
    int*    cnt   = (int*)   alloc(V_NEXT * 4);
    float*  sumA  = (float*) alloc(V_NEXT * 4);
    int*    offs  = (int*)   alloc(V_NEXT * 4);
    int*    cursor= (int*)   alloc(V_NEXT * 4);
    int*    bsum  = (int*)   alloc(256 * 4);
    int*    boff  = (int*)   alloc(256 * 4);
    int*    srcsA = (int*)   alloc((size_t)N_EDGE * 4);
    float*  valsA = (float*) alloc((size_t)N_EDGE * 4);
    int*    srcs0 = (int*)   alloc((size_t)N_EDGE * 4);
    float*  vals0 = (float*) alloc((size_t)N_EDGE * 4);
    int*    colof = (int*)   alloc(V_NEXT * 4);
    float*  valof = (float*) alloc(V_NEXT * 4);
    ushort* WresT = (ushort*)alloc(256 * 512 * 2);
    ushort* W0t   = (ushort*)alloc(512 * 512 * 2);
    ushort* W1cat = (ushort*)alloc(256 * 512 * 2);
    float*  biasUi= (float*) alloc(256 * 4);
    float*  psum0 = (float*) alloc(128 * 512 * 4);
    float*  psq0  = (float*) alloc(128 * 512 * 4);
    float*  sc0   = (float*) alloc(512 * 4);
    float*  sh0   = (float*) alloc(512 * 4);
    float*  psum1 = (float*) alloc(512 * 256 * 4);
    float*  psq1  = (float*) alloc(512 * 256 * 4);
    float*  sc1   = (float*) alloc(256 * 4);
    float*  sh1   = (float*) alloc(256 * 4);
    (void)ws_size; (void)in_sizes; (void)n_in; (void)out_size;

    // ---- prep + CSR build (independent of x) ----
    prep_weights_kernel<<<1024, 256, 0, stream>>>(W_res, Ui0_W, Uj0_W, Ui1_W, Uj1_W,
                                                  Ui1_b, b_res,
                                                  WresT, W0t, W1cat, biasUi);
    invert_up_kernel<<<NNZ_UP / 256, 256, 0, stream>>>(up_row, up_col, up_val, colof, valof);
    hipMemsetAsync(cnt,  0, (size_t)V_NEXT * 4, stream);
    hipMemsetAsync(sumA, 0, (size_t)V_NEXT * 4, stream);
    hist_kernel<<<N_EDGE / 256, 256, 0, stream>>>(e_dst, adjv, cnt, sumA);
    scan_block_kernel<<<256, 256, 0, stream>>>(cnt, offs, bsum);
    scan_top_kernel<<<1, 256, 0, stream>>>(bsum, boff);
    add_offs_kernel<<<256, 256, 0, stream>>>(offs, boff, cursor);
    fill_kernel<<<N_EDGE / 256, 256, 0, stream>>>(e_src, e_dst, adjv, colof, valof,
                                                  cursor, srcsA, valsA, srcs0, vals0);

    // ---- bn0 stats ----
    bn0_part_kernel<<<128, 256, 0, stream>>>(x, psum0, psq0);
    bn_finish_kernel<<<128, 256, 0, stream>>>(psum0, psq0, 128, 512, 1.0f / V_PREV,
                                              bn0_g, bn0_b, sc0, sh0);

    // ---- GEMM0 (fused bn0+relu+cast, XCD-grouped): XW, XNJ, XNI ----
    gemm0_fused_kernel<<<768, 256, 0, stream>>>(x, WresT, W0t, sc0, sh0, XW, XNJ, XNI);

    // ---- ECC layer 0 aggregation ----
    gather0_kernel<<<V_NEXT / 4, 256, 0, stream>>>(offs, cnt, srcs0, vals0,
                                                   colof, valof, sumA,
                                                   XNJ, XNI, Ui0_b, Uj0_b, X1);

    // ---- bn1 stats ----
    bn1_part_bf16_kernel<<<512, 256, 0, stream>>>(X1, psum1, psq1);
    bn_finish_kernel<<<64, 256, 0, stream>>>(psum1, psq1, 512, 256, 1.0f / V_NEXT,
                                             bn1_g, bn1_b, sc1, sh1);

    // ---- ECC layer 1 aggregation BEFORE the GEMM (commuted) ----
    gather1G_kernel<<<V_NEXT / 4, 256, 0, stream>>>(offs, cnt, srcsA, valsA,
                                                    X1, sc1, sh1, G);

    // ---- final GEMM: out = [H1|G] @ W1cat + biases + residual ----
    gemm_final_kernel<<<512, 256, 0, stream>>>(X1, G, W1cat, sc1, sh1,
                                               biasUi, Uj1_b, sumA,
                                               colof, valof, XW, out);
}